// Round 5
// baseline (281.759 us; speedup 1.0000x reference)
//
#include <hip/hip_runtime.h>

#define N_NODES 50000
#define N_EDGES 800000
#define NG      128
#define FIN     64
#define HD      108
#define SCAN_B  49          // ceil(50000/1024)

typedef __attribute__((ext_vector_type(8))) short s16x8;   // 8 bf16 = 4 VGPRs
typedef __attribute__((ext_vector_type(4))) float f32x4;

__device__ __forceinline__ unsigned short bf16_rne(float x) {
    unsigned u = __float_as_uint(x);
    u += 0x7FFFu + ((u >> 16) & 1u);
    return (unsigned short)(u >> 16);
}
__device__ __forceinline__ float bf16_to_f(unsigned u16) {
    return __uint_as_float(u16 << 16);
}

// ---------------------------------------------------------------------------
// Fused prep. block ranges:
// [0,1563) fconv | [1563,1759) hpad pad-zero | [1759,1805) wprep (182 tiles)
// [1805,1854) deg=0 | [1854,1868) gsum=0 | [1868] gcnt bsearch
// Weight tile map (26 kstiles x 7 nt, 512 shorts each):
//   emb kst 0..1 | p1 2..5 | n1 6..13 (K=256: ks<4 h rows, ks>=4 c rows)
//   p2 14..17 | n2 18..25
// ---------------------------------------------------------------------------
__global__ void prep_k(const float* __restrict__ feat, unsigned short* __restrict__ fbf,
                       unsigned short* __restrict__ hpad,
                       const float* __restrict__ W0, const float* __restrict__ W1,
                       const float* __restrict__ W2, const float* __restrict__ W3,
                       const float* __restrict__ W4, unsigned short* __restrict__ Wf,
                       int* __restrict__ deg, float* __restrict__ gsum,
                       const int* __restrict__ gids, int* __restrict__ gcnt) {
    int b = blockIdx.x, t = threadIdx.x;
    if (b < 1563) {                                   // feat f32 -> bf16, 8/thread
        int i = b * 256 + t;
        if (i < N_NODES * FIN / 8) {
            const float4* p = (const float4*)(feat + (size_t)i * 8);
            float4 a = p[0], c = p[1];
            s16x8 o;
            o[0] = (short)bf16_rne(a.x); o[1] = (short)bf16_rne(a.y);
            o[2] = (short)bf16_rne(a.z); o[3] = (short)bf16_rne(a.w);
            o[4] = (short)bf16_rne(c.x); o[5] = (short)bf16_rne(c.y);
            o[6] = (short)bf16_rne(c.z); o[7] = (short)bf16_rne(c.w);
            *(s16x8*)(fbf + (size_t)i * 8) = o;
        }
    } else if (b < 1759) {                            // hpad cols 112..127 = 0
        int i = (b - 1563) * 256 + t;
        if (i < N_NODES) {
            s16x8 z = {0, 0, 0, 0, 0, 0, 0, 0};
            *(s16x8*)(hpad + (size_t)i * 128 + 112) = z;
            *(s16x8*)(hpad + (size_t)i * 128 + 120) = z;
        }
    } else if (b < 1805) {                            // weight repack, 1 tile/wave
        int tile = (b - 1759) * 4 + (t >> 6), lane = t & 63;
        if (tile < 182) {
            int kst = tile / 7, nt = tile % 7;
            const float* W; int Kr, ksl, typ;
            if (kst < 2)       { W = W0; Kr = 64;  ksl = kst;      typ = 0; }
            else if (kst < 6)  { W = W1; Kr = 108; ksl = kst - 2;  typ = 0; }
            else if (kst < 14) { W = W2; Kr = 0;   ksl = kst - 6;  typ = 1; }
            else if (kst < 18) { W = W3; Kr = 108; ksl = kst - 14; typ = 0; }
            else               { W = W4; Kr = 0;   ksl = kst - 18; typ = 1; }
            int n = nt * 16 + (lane & 15);
            s16x8 o;
            #pragma unroll
            for (int j = 0; j < 8; ++j) {
                int k = ksl * 32 + (lane >> 4) * 8 + j;
                int row = -1;
                if (typ == 0) { if (k < Kr) row = k; }
                else {
                    if (k < HD) row = k;                              // h part
                    else if (k >= 128 && k < 128 + HD) row = HD + (k - 128); // c part
                }
                float v = (row >= 0 && n < HD) ? W[row * HD + n] : 0.0f;
                o[j] = (short)bf16_rne(v);
            }
            *(s16x8*)(Wf + (size_t)tile * 512 + lane * 8) = o;
        }
    } else if (b < 1854) {                            // deg = 0
        int i = (b - 1805) * 256 + t;
        if (i < N_NODES / 4) ((int4*)deg)[i] = (int4){0, 0, 0, 0};
    } else if (b < 1868) {                            // gsum = 0
        int i = (b - 1854) * 256 + t;
        if (i < NG * HD / 4) ((int4*)gsum)[i] = (int4){0, 0, 0, 0};
    } else {                                          // per-graph counts (sorted)
        int g = t;
        if (g < NG) {
            int lo = 0, hi = N_NODES;
            while (lo < hi) { int mid = (lo + hi) >> 1; if (gids[mid] < g) lo = mid + 1; else hi = mid; }
            int s = lo;
            lo = s; hi = N_NODES;
            while (lo < hi) { int mid = (lo + hi) >> 1; if (gids[mid] < g + 1) lo = mid + 1; else hi = mid; }
            gcnt[g] = lo - s;
        }
    }
}

// ---------------------------------------------------------------------------
// CSR construction
// ---------------------------------------------------------------------------
__global__ void count_k(const int* __restrict__ dst, int* __restrict__ deg,
                        int* __restrict__ pos) {
    int e = blockIdx.x * 256 + threadIdx.x;
    if (e < N_EDGES) pos[e] = atomicAdd(&deg[dst[e]], 1);
}

__global__ void scan1_k(const int* __restrict__ deg, int* __restrict__ rowp,
                        int* __restrict__ bsum) {
    __shared__ int s_w[16];
    int t = threadIdx.x, lane = t & 63, wid = t >> 6;
    int i = blockIdx.x * 1024 + t;
    int v = (i < N_NODES) ? deg[i] : 0;
    int x = v;
    #pragma unroll
    for (int off = 1; off < 64; off <<= 1) {
        int y = __shfl_up(x, off);
        if (lane >= off) x += y;
    }
    if (lane == 63) s_w[wid] = x;
    __syncthreads();
    if (t < 16) {
        int y = s_w[t];
        #pragma unroll
        for (int off = 1; off < 16; off <<= 1) {
            int z = __shfl_up(y, off);
            if (t >= off) y += z;
        }
        s_w[t] = y;
    }
    __syncthreads();
    int woff = wid ? s_w[wid - 1] : 0;
    if (i < N_NODES) rowp[i] = woff + x - v;
    if (t == 1023) bsum[blockIdx.x] = s_w[15];
}

__global__ void scan2_k(const int* __restrict__ bsum, int* __restrict__ boff,
                        int* __restrict__ rowp) {
    int t = threadIdx.x;
    int v = (t < SCAN_B) ? bsum[t] : 0;
    int x = v;
    #pragma unroll
    for (int off = 1; off < 64; off <<= 1) {
        int y = __shfl_up(x, off);
        if (t >= off) x += y;
    }
    if (t < SCAN_B) boff[t] = x - v;
    if (t == SCAN_B - 1) rowp[N_NODES] = x;
}

__global__ void scan3_k(int* __restrict__ rowp, const int* __restrict__ boff) {
    int i = blockIdx.x * 1024 + threadIdx.x;
    if (i < N_NODES) rowp[i] += boff[blockIdx.x];
}

__global__ void fill_k(const int* __restrict__ src, const int* __restrict__ dst,
                       const int* __restrict__ rowp, const int* __restrict__ pos,
                       int* __restrict__ csr) {
    int e = blockIdx.x * 256 + threadIdx.x;
    if (e < N_EDGES) csr[rowp[dst[e]] + pos[e]] = src[e];
}

// ---------------------------------------------------------------------------
// embed + pool1: hpad = feat @ Wemb + b ; m_cb = relu(hpad @ Wp1 + bp1)
// m layout: col-block-major m[cb][node][16] (cb = col/16, 7 blocks, cols<112)
// ---------------------------------------------------------------------------
__global__ __launch_bounds__(256) void embed_k(
    const unsigned short* __restrict__ A,
    const unsigned short* __restrict__ Wf, const float* __restrict__ bias,
    const unsigned short* __restrict__ Wfp, const float* __restrict__ biasp,
    unsigned short* __restrict__ hpad, unsigned short* __restrict__ m_out) {
    __shared__ unsigned short s_t[4][16][136];
    int t = threadIdx.x, lane = t & 63, wave = t >> 6;
    int wrow = (blockIdx.x * 4 + wave) * 16;
    if (wrow >= N_NODES) return;
    int l15 = lane & 15, lg = lane >> 4;

    f32x4 acc[7];
    #pragma unroll
    for (int nt = 0; nt < 7; ++nt) acc[nt] = (f32x4){0.f, 0.f, 0.f, 0.f};
    const unsigned short* arow = A + (size_t)(wrow + l15) * FIN + lg * 8;
    #pragma unroll
    for (int ks = 0; ks < 2; ++ks) {
        s16x8 a = *(const s16x8*)(arow + ks * 32);
        const unsigned short* wp = Wf + ((size_t)(ks * 7) * 64 + lane) * 8;
        #pragma unroll
        for (int nt = 0; nt < 7; ++nt) {
            s16x8 bfr = *(const s16x8*)(wp + (size_t)nt * 512);
            acc[nt] = __builtin_amdgcn_mfma_f32_16x16x32_bf16(a, bfr, acc[nt], 0, 0, 0);
        }
    }
    // epilogue: + bias, write hpad (bf16) + LDS transpose
    #pragma unroll
    for (int nt = 0; nt < 7; ++nt) {
        int col = nt * 16 + l15;
        bool valid = (col < HD);
        float bv = valid ? bias[col] : 0.0f;
        #pragma unroll
        for (int r = 0; r < 4; ++r) {
            unsigned short hb = valid ? bf16_rne(acc[nt][r] + bv) : 0;
            int lrow = lg * 4 + r;
            hpad[(size_t)(wrow + lrow) * 128 + col] = hb;   // col <= 111
            s_t[wave][lrow][col] = hb;
        }
    }
    for (int z = lane; z < 160; z += 64) {            // zero LDS cols 108..127
        int row = z / 10, dc = z % 10;
        *(unsigned*)&s_t[wave][row][108 + dc * 2] = 0u;
    }
    // pool1
    f32x4 accp[7];
    #pragma unroll
    for (int nt = 0; nt < 7; ++nt) accp[nt] = (f32x4){0.f, 0.f, 0.f, 0.f};
    #pragma unroll
    for (int ks = 0; ks < 4; ++ks) {
        s16x8 a = *(const s16x8*)&s_t[wave][l15][ks * 32 + lg * 8];
        const unsigned short* wp = Wfp + ((size_t)(ks * 7) * 64 + lane) * 8;
        #pragma unroll
        for (int nt = 0; nt < 7; ++nt) {
            s16x8 bfr = *(const s16x8*)(wp + (size_t)nt * 512);
            accp[nt] = __builtin_amdgcn_mfma_f32_16x16x32_bf16(a, bfr, accp[nt], 0, 0, 0);
        }
    }
    #pragma unroll
    for (int nt = 0; nt < 7; ++nt) {
        int col = nt * 16 + l15;
        float bv = (col < HD) ? biasp[col] : 0.0f;
        #pragma unroll
        for (int r = 0; r < 4; ++r) {
            int row = wrow + lg * 4 + r;
            m_out[((size_t)nt * N_NODES + row) * 16 + l15] =
                bf16_rne(fmaxf(accp[nt][r] + bv, 0.0f));
        }
    }
}

// ---------------------------------------------------------------------------
// Fused aggregate + apply (+pool or +graph-sum).
// Per wave: 16 nodes. Gather c = mean of m_in[src] rows directly into MFMA
// c-fragments (K 128..255); h-fragments from hpad (K 0..127). Then
// bundle = [h,c] @ Wn + bn, L2-normalize, residual, and either pool -> m_out
// or per-graph sum atomics.
// ---------------------------------------------------------------------------
template <bool FINAL>
__global__ __launch_bounds__(256) void agg_gemm_k(
    unsigned short* __restrict__ hpad,
    const unsigned short* __restrict__ m_in,
    const int* __restrict__ rowp, const int* __restrict__ csr,
    const unsigned short* __restrict__ Wf, const float* __restrict__ bias,
    const unsigned short* __restrict__ Wfp, const float* __restrict__ biasp,
    unsigned short* __restrict__ m_out,
    const int* __restrict__ gids, float* __restrict__ gsum) {
    int t = threadIdx.x, lane = t & 63, wave = t >> 6;
    int wrow = (blockIdx.x * 4 + wave) * 16;
    if (wrow >= N_NODES) return;
    int l15 = lane & 15, lg = lane >> 4;
    int v = wrow + l15;

    // ---- gather: accumulate c fragments (f32) over incoming edges ----
    int beg = rowp[v];
    int degv = rowp[v + 1] - beg;
    float inv = (degv > 0) ? 1.0f / (float)degv : 0.0f;
    float cacc[4][8];
    #pragma unroll
    for (int ks = 0; ks < 4; ++ks)
        #pragma unroll
        for (int j = 0; j < 8; ++j) cacc[ks][j] = 0.0f;

    for (int d = 0; __any(d < degv); ++d) {
        if (d < degv) {
            int srcv = csr[beg + d];
            #pragma unroll
            for (int ks = 0; ks < 4; ++ks) {
                int cb = ks * 2 + (lg >> 1);
                if (cb < 7) {
                    s16x8 mm = *(const s16x8*)(m_in +
                        ((size_t)cb * N_NODES + srcv) * 16 + (lg & 1) * 8);
                    #pragma unroll
                    for (int j = 0; j < 8; ++j)
                        cacc[ks][j] += bf16_to_f((unsigned short)mm[j]);
                }
            }
        }
    }

    // ---- GEMM: K=256 (h: ks 0..3 from hpad, c: ks 4..7 from cacc) ----
    f32x4 acc[7];
    #pragma unroll
    for (int nt = 0; nt < 7; ++nt) acc[nt] = (f32x4){0.f, 0.f, 0.f, 0.f};
    const unsigned short* arow = hpad + (size_t)v * 128 + lg * 8;
    #pragma unroll
    for (int ks = 0; ks < 4; ++ks) {
        s16x8 a = *(const s16x8*)(arow + ks * 32);
        const unsigned short* wp = Wf + ((size_t)(ks * 7) * 64 + lane) * 8;
        #pragma unroll
        for (int nt = 0; nt < 7; ++nt) {
            s16x8 bfr = *(const s16x8*)(wp + (size_t)nt * 512);
            acc[nt] = __builtin_amdgcn_mfma_f32_16x16x32_bf16(a, bfr, acc[nt], 0, 0, 0);
        }
    }
    #pragma unroll
    for (int ks = 0; ks < 4; ++ks) {
        s16x8 ca;
        #pragma unroll
        for (int j = 0; j < 8; ++j) ca[j] = (short)bf16_rne(cacc[ks][j] * inv);
        const unsigned short* wp = Wf + ((size_t)((4 + ks) * 7) * 64 + lane) * 8;
        #pragma unroll
        for (int nt = 0; nt < 7; ++nt) {
            s16x8 bfr = *(const s16x8*)(wp + (size_t)nt * 512);
            acc[nt] = __builtin_amdgcn_mfma_f32_16x16x32_bf16(ca, bfr, acc[nt], 0, 0, 0);
        }
    }

    // ---- epilogue: bias, L2-norm, residual ----
    float vals[7][4];
    float ss[4] = {0.f, 0.f, 0.f, 0.f};
    #pragma unroll
    for (int nt = 0; nt < 7; ++nt) {
        int col = nt * 16 + l15;
        bool valid = (col < HD);
        float bv = valid ? bias[col] : 0.0f;
        #pragma unroll
        for (int r = 0; r < 4; ++r) {
            float x = valid ? (acc[nt][r] + bv) : 0.0f;
            vals[nt][r] = x;
            ss[r] += x * x;
        }
    }
    #pragma unroll
    for (int r = 0; r < 4; ++r) {
        ss[r] += __shfl_xor(ss[r], 1);
        ss[r] += __shfl_xor(ss[r], 2);
        ss[r] += __shfl_xor(ss[r], 4);
        ss[r] += __shfl_xor(ss[r], 8);
    }
    float rn[4];
    #pragma unroll
    for (int r = 0; r < 4; ++r) rn[r] = 1.0f / fmaxf(sqrtf(ss[r]), 1e-12f);
    #pragma unroll
    for (int nt = 0; nt < 7; ++nt) {
        int col = nt * 16 + l15;
        bool valid = (col < HD);
        #pragma unroll
        for (int r = 0; r < 4; ++r) {
            int row = wrow + lg * 4 + r;
            float hv = valid ? bf16_to_f(hpad[(size_t)row * 128 + col]) : 0.0f;
            vals[nt][r] = hv + fmaxf(vals[nt][r] * rn[r], 0.0f);
        }
    }

    if constexpr (FINAL) {                            // per-graph mean accumulation
        int g0 = gids[wrow], g15 = gids[wrow + 15];
        if (g0 == g15) {
            #pragma unroll
            for (int nt = 0; nt < 7; ++nt) {
                int col = nt * 16 + l15;
                float cs = vals[nt][0] + vals[nt][1] + vals[nt][2] + vals[nt][3];
                cs += __shfl_xor(cs, 16);
                cs += __shfl_xor(cs, 32);
                if (lane < 16 && col < HD) atomicAdd(&gsum[g0 * HD + col], cs);
            }
        } else {
            int gr[4];
            #pragma unroll
            for (int r = 0; r < 4; ++r) gr[r] = gids[wrow + lg * 4 + r];
            #pragma unroll
            for (int nt = 0; nt < 7; ++nt) {
                int col = nt * 16 + l15;
                if (col >= HD) continue;
                #pragma unroll
                for (int r = 0; r < 4; ++r)
                    atomicAdd(&gsum[gr[r] * HD + col], vals[nt][r]);
            }
        }
    } else {
        // write h' + LDS transpose, then pool -> m_out (col-block layout)
        __shared__ unsigned short s_t[4][16][136];
        #pragma unroll
        for (int nt = 0; nt < 7; ++nt) {
            int col = nt * 16 + l15;
            bool valid = (col < HD);
            #pragma unroll
            for (int r = 0; r < 4; ++r) {
                unsigned short hb = valid ? bf16_rne(vals[nt][r]) : 0;
                int lrow = lg * 4 + r;
                hpad[(size_t)(wrow + lrow) * 128 + col] = hb;
                s_t[wave][lrow][col] = hb;
            }
        }
        for (int z = lane; z < 160; z += 64) {
            int row = z / 10, dc = z % 10;
            *(unsigned*)&s_t[wave][row][108 + dc * 2] = 0u;
        }
        f32x4 accp[7];
        #pragma unroll
        for (int nt = 0; nt < 7; ++nt) accp[nt] = (f32x4){0.f, 0.f, 0.f, 0.f};
        #pragma unroll
        for (int ks = 0; ks < 4; ++ks) {
            s16x8 a = *(const s16x8*)&s_t[wave][l15][ks * 32 + lg * 8];
            const unsigned short* wp = Wfp + ((size_t)(ks * 7) * 64 + lane) * 8;
            #pragma unroll
            for (int nt = 0; nt < 7; ++nt) {
                s16x8 bfr = *(const s16x8*)(wp + (size_t)nt * 512);
                accp[nt] = __builtin_amdgcn_mfma_f32_16x16x32_bf16(a, bfr, accp[nt], 0, 0, 0);
            }
        }
        #pragma unroll
        for (int nt = 0; nt < 7; ++nt) {
            int col = nt * 16 + l15;
            float bv = (col < HD) ? biasp[col] : 0.0f;
            #pragma unroll
            for (int r = 0; r < 4; ++r) {
                int row = wrow + lg * 4 + r;
                m_out[((size_t)nt * N_NODES + row) * 16 + l15] =
                    bf16_rne(fmaxf(accp[nt][r] + bv, 0.0f));
            }
        }
    }
}

__global__ void finalize_k(const float* __restrict__ gsum, const int* __restrict__ gcnt,
                           float* __restrict__ out) {
    int i = blockIdx.x * 256 + threadIdx.x;
    if (i < NG * HD) {
        int g = i / HD;
        int cnt = gcnt[g];
        float inv = (cnt > 0) ? 1.0f / (float)cnt : 0.0f;
        out[i] = gsum[i] * inv;
    }
}

// ---------------------------------------------------------------------------
extern "C" void kernel_launch(void* const* d_in, const int* in_sizes, int n_in,
                              void* d_out, int out_size, void* d_ws, size_t ws_size,
                              hipStream_t stream) {
    const float* feat = (const float*)d_in[0];
    const int* src  = (const int*)d_in[4];
    const int* dst  = (const int*)d_in[5];
    const int* gids = (const int*)d_in[6];
    const float* Wemb = (const float*)d_in[7];
    const float* bemb = (const float*)d_in[8];
    const float* Wp1  = (const float*)d_in[9];
    const float* bp1  = (const float*)d_in[10];
    const float* Wn1  = (const float*)d_in[11];
    const float* bn1  = (const float*)d_in[12];
    const float* Wp2  = (const float*)d_in[13];
    const float* bp2  = (const float*)d_in[14];
    const float* Wn2  = (const float*)d_in[15];
    const float* bn2  = (const float*)d_in[16];
    float* out = (float*)d_out;
    (void)in_sizes; (void)n_in; (void)out_size; (void)ws_size;

    char* ws = (char*)d_ws;
    size_t off = 0;
    auto carve = [&](size_t bytes) -> char* {
        char* p = ws + off;
        off = (off + bytes + 255) & ~(size_t)255;
        return p;
    };
    unsigned short* hpad = (unsigned short*)carve((size_t)N_NODES * 128 * 2);
    unsigned short* m_a  = (unsigned short*)carve((size_t)7 * N_NODES * 16 * 2);
    unsigned short* m_b  = (unsigned short*)carve((size_t)7 * N_NODES * 16 * 2);
    unsigned short* fbf  = (unsigned short*)carve((size_t)N_NODES * FIN * 2);
    unsigned short* Wf   = (unsigned short*)carve((size_t)182 * 512 * 2);
    int* deg  = (int*)carve((size_t)N_NODES * 4);
    int* rowp = (int*)carve((size_t)(N_NODES + 1) * 4);
    int* pos  = (int*)carve((size_t)N_EDGES * 4);
    int* csr  = (int*)carve((size_t)N_EDGES * 4);
    int* bsum = (int*)carve((size_t)SCAN_B * 4);
    int* boff = (int*)carve((size_t)SCAN_B * 4);
    float* gsum = (float*)carve((size_t)NG * HD * 4);
    int*   gcnt = (int*)carve((size_t)NG * 4);

    // fused prep (also zeroes deg/gsum; no hipMemset anywhere)
    prep_k<<<1869, 256, 0, stream>>>(feat, fbf, hpad, Wemb, Wp1, Wn1, Wp2, Wn2, Wf,
                                     deg, gsum, gids, gcnt);

    count_k<<<(N_EDGES + 255) / 256, 256, 0, stream>>>(dst, deg, pos);
    scan1_k<<<SCAN_B, 1024, 0, stream>>>(deg, rowp, bsum);
    scan2_k<<<1, 64, 0, stream>>>(bsum, boff, rowp);
    scan3_k<<<SCAN_B, 1024, 0, stream>>>(rowp, boff);
    fill_k<<<(N_EDGES + 255) / 256, 256, 0, stream>>>(src, dst, rowp, pos, csr);

    const int GB = (N_NODES / 16 + 3) / 4;           // 782 blocks x 4 waves
    unsigned short* Wf_emb = Wf + (size_t)0   * 512;
    unsigned short* Wf_p1  = Wf + (size_t)14  * 512;
    unsigned short* Wf_n1  = Wf + (size_t)42  * 512;
    unsigned short* Wf_p2  = Wf + (size_t)98  * 512;
    unsigned short* Wf_n2  = Wf + (size_t)126 * 512;

    // embed + pool1 -> hpad, m_a
    embed_k<<<GB, 256, 0, stream>>>(fbf, Wf_emb, bemb, Wf_p1, bp1, hpad, m_a);
    // layer 1: aggregate(m_a) + apply1 + pool2 -> hpad, m_b
    agg_gemm_k<false><<<GB, 256, 0, stream>>>(hpad, m_a, rowp, csr, Wf_n1, bn1,
                                              Wf_p2, bp2, m_b, nullptr, nullptr);
    // layer 2: aggregate(m_b) + apply2 -> graph sums
    agg_gemm_k<true><<<GB, 256, 0, stream>>>(hpad, m_b, rowp, csr, Wf_n2, bn2,
                                             nullptr, nullptr, nullptr, gids, gsum);

    finalize_k<<<(NG * HD + 255) / 256, 256, 0, stream>>>(gsum, gcnt, out);
}

// Round 6
// 201.410 us; speedup vs baseline: 1.3989x; 1.3989x over previous
//
#include <hip/hip_runtime.h>

#define N_NODES 50000
#define N_EDGES 800000
#define NG      128
#define FIN     64
#define HD      108
#define SCAN_B  49          // ceil(50000/1024)

typedef __attribute__((ext_vector_type(8))) short s16x8;   // 8 bf16 = 4 VGPRs
typedef __attribute__((ext_vector_type(4))) float f32x4;

__device__ __forceinline__ unsigned short bf16_rne(float x) {
    unsigned u = __float_as_uint(x);
    u += 0x7FFFu + ((u >> 16) & 1u);
    return (unsigned short)(u >> 16);
}
__device__ __forceinline__ float bf16_to_f(unsigned u16) {
    return __uint_as_float(u16 << 16);
}

// ---------------------------------------------------------------------------
// Fused prep: fconv | hc pad zero | weight repack | deg zero | gsum zero | gcnt
// block ranges: [0,1563) fconv, [1563,1759) zeropad, [1759,1801) wprep,
//               [1801,1850) deg, [1850,1864) gsum, [1864] gcnt
// Weight tiles (24 kst x 7 nt): emb 0..1 | p1 2..5 | n1 6..12 | p2 13..16 | n2 17..23
// ---------------------------------------------------------------------------
__global__ void prep_k(const float* __restrict__ feat, unsigned short* __restrict__ fbf,
                       unsigned short* __restrict__ hc,
                       const float* __restrict__ W0, const float* __restrict__ W1,
                       const float* __restrict__ W2, const float* __restrict__ W3,
                       const float* __restrict__ W4, unsigned short* __restrict__ Wf,
                       int* __restrict__ deg, float* __restrict__ gsum,
                       const int* __restrict__ gids, int* __restrict__ gcnt) {
    int b = blockIdx.x, t = threadIdx.x;
    if (b < 1563) {                                   // feat f32 -> bf16, 8/thread
        int i = b * 256 + t;
        if (i < N_NODES * FIN / 8) {
            const float4* p = (const float4*)(feat + (size_t)i * 8);
            float4 a = p[0], c = p[1];
            s16x8 o;
            o[0] = (short)bf16_rne(a.x); o[1] = (short)bf16_rne(a.y);
            o[2] = (short)bf16_rne(a.z); o[3] = (short)bf16_rne(a.w);
            o[4] = (short)bf16_rne(c.x); o[5] = (short)bf16_rne(c.y);
            o[6] = (short)bf16_rne(c.z); o[7] = (short)bf16_rne(c.w);
            *(s16x8*)(fbf + (size_t)i * 8) = o;
        }
    } else if (b < 1759) {                            // hc cols 216..223 = 0
        int i = (b - 1563) * 256 + t;
        if (i < N_NODES) {
            s16x8 z = {0, 0, 0, 0, 0, 0, 0, 0};
            *(s16x8*)(hc + (size_t)i * 224 + 216) = z;
        }
    } else if (b < 1801) {                            // weight repack, 1 tile/wave
        int tile = (b - 1759) * 4 + (t >> 6), lane = t & 63;
        if (tile < 168) {
            int kst = tile / 7, nt = tile % 7;
            const float* W; int Kr, ks;
            if (kst < 2)       { W = W0; Kr = 64;  ks = kst;      }
            else if (kst < 6)  { W = W1; Kr = 108; ks = kst - 2;  }
            else if (kst < 13) { W = W2; Kr = 216; ks = kst - 6;  }
            else if (kst < 17) { W = W3; Kr = 108; ks = kst - 13; }
            else               { W = W4; Kr = 216; ks = kst - 17; }
            int n = nt * 16 + (lane & 15);
            s16x8 o;
            #pragma unroll
            for (int j = 0; j < 8; ++j) {
                int k = ks * 32 + (lane >> 4) * 8 + j;
                float v = (k < Kr && n < HD) ? W[k * HD + n] : 0.0f;
                o[j] = (short)bf16_rne(v);
            }
            *(s16x8*)(Wf + (size_t)tile * 512 + lane * 8) = o;
        }
    } else if (b < 1850) {                            // deg = 0
        int i = (b - 1801) * 256 + t;
        if (i < N_NODES / 4) ((int4*)deg)[i] = (int4){0, 0, 0, 0};
    } else if (b < 1864) {                            // gsum = 0
        int i = (b - 1850) * 256 + t;
        if (i < NG * HD / 4) ((int4*)gsum)[i] = (int4){0, 0, 0, 0};
    } else {                                          // per-graph counts (sorted)
        int g = t;
        if (g < NG) {
            int lo = 0, hi = N_NODES;
            while (lo < hi) { int mid = (lo + hi) >> 1; if (gids[mid] < g) lo = mid + 1; else hi = mid; }
            int s = lo;
            lo = s; hi = N_NODES;
            while (lo < hi) { int mid = (lo + hi) >> 1; if (gids[mid] < g + 1) lo = mid + 1; else hi = mid; }
            gcnt[g] = lo - s;
        }
    }
}

// ---------------------------------------------------------------------------
// CSR construction
// ---------------------------------------------------------------------------
__global__ void count_k(const int* __restrict__ dst, int* __restrict__ deg,
                        int* __restrict__ pos) {
    int e = blockIdx.x * 256 + threadIdx.x;
    if (e < N_EDGES) pos[e] = atomicAdd(&deg[dst[e]], 1);
}

__global__ void scan1_k(const int* __restrict__ deg, int* __restrict__ rowp,
                        int* __restrict__ bsum) {
    __shared__ int s_w[16];
    int t = threadIdx.x, lane = t & 63, wid = t >> 6;
    int i = blockIdx.x * 1024 + t;
    int v = (i < N_NODES) ? deg[i] : 0;
    int x = v;
    #pragma unroll
    for (int off = 1; off < 64; off <<= 1) {
        int y = __shfl_up(x, off);
        if (lane >= off) x += y;
    }
    if (lane == 63) s_w[wid] = x;
    __syncthreads();
    if (t < 16) {
        int y = s_w[t];
        #pragma unroll
        for (int off = 1; off < 16; off <<= 1) {
            int z = __shfl_up(y, off);
            if (t >= off) y += z;
        }
        s_w[t] = y;
    }
    __syncthreads();
    int woff = wid ? s_w[wid - 1] : 0;
    if (i < N_NODES) rowp[i] = woff + x - v;
    if (t == 1023) bsum[blockIdx.x] = s_w[15];
}

__global__ void scan2_k(const int* __restrict__ bsum, int* __restrict__ boff,
                        int* __restrict__ rowp) {
    int t = threadIdx.x;
    int v = (t < SCAN_B) ? bsum[t] : 0;
    int x = v;
    #pragma unroll
    for (int off = 1; off < 64; off <<= 1) {
        int y = __shfl_up(x, off);
        if (t >= off) x += y;
    }
    if (t < SCAN_B) boff[t] = x - v;
    if (t == SCAN_B - 1) rowp[N_NODES] = x;
}

__global__ void scan3_k(int* __restrict__ rowp, const int* __restrict__ boff) {
    int i = blockIdx.x * 1024 + threadIdx.x;
    if (i < N_NODES) rowp[i] += boff[blockIdx.x];
}

__global__ void fill_k(const int* __restrict__ src, const int* __restrict__ dst,
                       const int* __restrict__ rowp, const int* __restrict__ pos,
                       int* __restrict__ csr) {
    int e = blockIdx.x * 256 + threadIdx.x;
    if (e < N_EDGES) csr[rowp[dst[e]] + pos[e]] = src[e];
}

// ---------------------------------------------------------------------------
// Fused GEMM. One wave = 16 nodes x 112 cols. EPI: 0=embed+pool, 2=apply+pool,
// 3=apply-final(graph-sum atomics). Pool output m is CHUNKED:
//   m[ch][node][32] bf16, ch = col/28, within = col%28 (cols 28..31 pad).
// Chunk = 3.2 MB -> fits one XCD's 4 MB L2 for the gather kernel.
// ---------------------------------------------------------------------------
template <int KSTEPS, int EPI>
__global__ __launch_bounds__(256) void gemm_k(
    const unsigned short* __restrict__ A, int strideA,
    const unsigned short* __restrict__ Wf, const float* __restrict__ bias,
    const unsigned short* __restrict__ Wfp, const float* __restrict__ biasp,
    unsigned short* __restrict__ hc, unsigned short* __restrict__ m_out,
    const int* __restrict__ gids, float* __restrict__ gsum) {
    __shared__ unsigned short s_t[4][16][136];
    int t = threadIdx.x, lane = t & 63, wave = t >> 6;
    int wrow = (blockIdx.x * 4 + wave) * 16;
    if (wrow >= N_NODES) return;
    int l15 = lane & 15, lg = lane >> 4;

    f32x4 acc[7];
    #pragma unroll
    for (int nt = 0; nt < 7; ++nt) acc[nt] = (f32x4){0.f, 0.f, 0.f, 0.f};

    const unsigned short* arow = A + (size_t)(wrow + l15) * strideA + lg * 8;
    #pragma unroll
    for (int ks = 0; ks < KSTEPS; ++ks) {
        s16x8 a = *(const s16x8*)(arow + ks * 32);
        const unsigned short* wp = Wf + ((size_t)(ks * 7) * 64 + lane) * 8;
        #pragma unroll
        for (int nt = 0; nt < 7; ++nt) {
            s16x8 bfr = *(const s16x8*)(wp + (size_t)nt * 512);
            acc[nt] = __builtin_amdgcn_mfma_f32_16x16x32_bf16(a, bfr, acc[nt], 0, 0, 0);
        }
    }

    // D layout: col = nt*16 + l15, row(local) = lg*4 + r
    float vals[7][4];
    if (EPI == 0) {                                   // embed: + bias
        #pragma unroll
        for (int nt = 0; nt < 7; ++nt) {
            int col = nt * 16 + l15;
            float bv = (col < HD) ? bias[col] : 0.0f;
            #pragma unroll
            for (int r = 0; r < 4; ++r) vals[nt][r] = acc[nt][r] + bv;
        }
    } else {                                          // apply: norm + residual
        float ss[4] = {0.f, 0.f, 0.f, 0.f};
        #pragma unroll
        for (int nt = 0; nt < 7; ++nt) {
            int col = nt * 16 + l15;
            bool valid = (col < HD);
            float bv = valid ? bias[col] : 0.0f;
            #pragma unroll
            for (int r = 0; r < 4; ++r) {
                float v = valid ? (acc[nt][r] + bv) : 0.0f;
                vals[nt][r] = v;
                ss[r] += v * v;
            }
        }
        #pragma unroll
        for (int r = 0; r < 4; ++r) {
            ss[r] += __shfl_xor(ss[r], 1);
            ss[r] += __shfl_xor(ss[r], 2);
            ss[r] += __shfl_xor(ss[r], 4);
            ss[r] += __shfl_xor(ss[r], 8);
        }
        float rn[4];
        #pragma unroll
        for (int r = 0; r < 4; ++r) rn[r] = 1.0f / fmaxf(sqrtf(ss[r]), 1e-12f);
        #pragma unroll
        for (int nt = 0; nt < 7; ++nt) {
            int col = nt * 16 + l15;
            bool valid = (col < HD);
            #pragma unroll
            for (int r = 0; r < 4; ++r) {
                int row = wrow + lg * 4 + r;
                float hv = valid ? bf16_to_f(hc[(size_t)row * 224 + col]) : 0.0f;
                vals[nt][r] = hv + fmaxf(vals[nt][r] * rn[r], 0.0f);
            }
        }
    }

    if (EPI == 3) {                                   // graph-mean accumulation
        int g0 = gids[wrow], g15 = gids[wrow + 15];
        if (g0 == g15) {
            #pragma unroll
            for (int nt = 0; nt < 7; ++nt) {
                int col = nt * 16 + l15;
                float cs = vals[nt][0] + vals[nt][1] + vals[nt][2] + vals[nt][3];
                cs += __shfl_xor(cs, 16);
                cs += __shfl_xor(cs, 32);
                if (lane < 16 && col < HD) atomicAdd(&gsum[g0 * HD + col], cs);
            }
        } else {
            int gr[4];
            #pragma unroll
            for (int r = 0; r < 4; ++r) gr[r] = gids[wrow + lg * 4 + r];
            #pragma unroll
            for (int nt = 0; nt < 7; ++nt) {
                int col = nt * 16 + l15;
                if (col >= HD) continue;
                #pragma unroll
                for (int r = 0; r < 4; ++r)
                    atomicAdd(&gsum[gr[r] * HD + col], vals[nt][r]);
            }
        }
        return;
    }

    // write h (bf16) to hc cols 0..107 and stage into LDS for the pool GEMM
    #pragma unroll
    for (int nt = 0; nt < 7; ++nt) {
        int col = nt * 16 + l15;
        #pragma unroll
        for (int r = 0; r < 4; ++r) {
            unsigned short hb = bf16_rne(vals[nt][r]);
            int lrow = lg * 4 + r;
            if (col < HD) hc[(size_t)(wrow + lrow) * 224 + col] = hb;
            s_t[wave][lrow][col] = (col < HD) ? hb : 0;
        }
    }
    // zero LDS cols 108..127 (pool reads k<128; zero-weight cols must not be NaN)
    for (int z = lane; z < 160; z += 64) {
        int row = z / 10, dc = z % 10;
        *(unsigned*)&s_t[wave][row][108 + dc * 2] = 0u;
    }

    // pool: m = relu(h @ Wp + bp), A-fragments from LDS transpose
    f32x4 accp[7];
    #pragma unroll
    for (int nt = 0; nt < 7; ++nt) accp[nt] = (f32x4){0.f, 0.f, 0.f, 0.f};
    #pragma unroll
    for (int ks = 0; ks < 4; ++ks) {
        s16x8 a = *(const s16x8*)&s_t[wave][l15][ks * 32 + lg * 8];
        const unsigned short* wp = Wfp + ((size_t)(ks * 7) * 64 + lane) * 8;
        #pragma unroll
        for (int nt = 0; nt < 7; ++nt) {
            s16x8 bfr = *(const s16x8*)(wp + (size_t)nt * 512);
            accp[nt] = __builtin_amdgcn_mfma_f32_16x16x32_bf16(a, bfr, accp[nt], 0, 0, 0);
        }
    }
    #pragma unroll
    for (int nt = 0; nt < 7; ++nt) {
        int col = nt * 16 + l15;                      // 0..111
        int ch = col / 28, wi = col - ch * 28;        // chunked m layout
        float bv = (col < HD) ? biasp[col] : 0.0f;
        #pragma unroll
        for (int r = 0; r < 4; ++r) {
            int row = wrow + lg * 4 + r;
            m_out[((size_t)ch * N_NODES + row) * 32 + wi] =
                bf16_rne(fmaxf(accp[nt][r] + bv, 0.0f));
        }
    }
}

// ---------------------------------------------------------------------------
// Chunked aggregation: c[v] = mean of m[src] rows, one col-chunk per XCD.
// chunk = blockIdx & 3 (round-robin XCD dispatch => XCD x serves chunk x&3,
// 3.2 MB chunk stays L2-resident). Per wave: 16 nodes x 4 lanes; each lane
// reads 16 B (8 cols incl pad) per edge -> 64 B/line per node-edge.
// ---------------------------------------------------------------------------
__global__ __launch_bounds__(256) void aggregate_k(
    const unsigned short* __restrict__ m,
    const int* __restrict__ rowp, const int* __restrict__ csr,
    unsigned short* __restrict__ hc) {
    int chunk = blockIdx.x & 3;
    int nblk  = blockIdx.x >> 2;
    int t = threadIdx.x, lane = t & 63, wave = t >> 6;
    int v = nblk * 64 + wave * 16 + (lane >> 2);
    if (v >= N_NODES) return;
    int co = (lane & 3) * 8;                          // within-chunk col offset
    const unsigned short* mc = m + (size_t)chunk * N_NODES * 32 + co;
    int beg = rowp[v], end = rowp[v + 1];
    float s[8] = {0.f, 0.f, 0.f, 0.f, 0.f, 0.f, 0.f, 0.f};
    int i = beg;
    for (; i + 1 < end; i += 2) {
        int sv0 = csr[i], sv1 = csr[i + 1];
        s16x8 a = *(const s16x8*)(mc + (size_t)sv0 * 32);
        s16x8 b = *(const s16x8*)(mc + (size_t)sv1 * 32);
        #pragma unroll
        for (int j = 0; j < 8; ++j)
            s[j] += bf16_to_f((unsigned short)a[j]) + bf16_to_f((unsigned short)b[j]);
    }
    if (i < end) {
        int sv = csr[i];
        s16x8 a = *(const s16x8*)(mc + (size_t)sv * 32);
        #pragma unroll
        for (int j = 0; j < 8; ++j) s[j] += bf16_to_f((unsigned short)a[j]);
    }
    int degv = end - beg;
    float inv = (degv > 0) ? 1.0f / (float)degv : 0.0f;
    int gcol = chunk * 28 + co;                       // global c col of j=0
    int nv = 28 - co; if (nv > 8) nv = 8;             // within-chunk validity
    if (gcol + nv > HD) nv = HD - gcol;               // chunk 3 tail trim
    if (nv > 0) {
        unsigned short* dstp = hc + (size_t)v * 224 + HD + gcol;
        #pragma unroll
        for (int j2 = 0; j2 < 4; ++j2) {
            if (j2 * 2 < nv) {
                unsigned pk = (unsigned)bf16_rne(s[2 * j2] * inv) |
                              ((unsigned)bf16_rne(s[2 * j2 + 1] * inv) << 16);
                *(unsigned*)(dstp + 2 * j2) = pk;
            }
        }
    }
}

__global__ void finalize_k(const float* __restrict__ gsum, const int* __restrict__ gcnt,
                           float* __restrict__ out) {
    int i = blockIdx.x * 256 + threadIdx.x;
    if (i < NG * HD) {
        int g = i / HD;
        int cnt = gcnt[g];
        float inv = (cnt > 0) ? 1.0f / (float)cnt : 0.0f;
        out[i] = gsum[i] * inv;
    }
}

// ---------------------------------------------------------------------------
extern "C" void kernel_launch(void* const* d_in, const int* in_sizes, int n_in,
                              void* d_out, int out_size, void* d_ws, size_t ws_size,
                              hipStream_t stream) {
    const float* feat = (const float*)d_in[0];
    const int* src  = (const int*)d_in[4];
    const int* dst  = (const int*)d_in[5];
    const int* gids = (const int*)d_in[6];
    const float* Wemb = (const float*)d_in[7];
    const float* bemb = (const float*)d_in[8];
    const float* Wp1  = (const float*)d_in[9];
    const float* bp1  = (const float*)d_in[10];
    const float* Wn1  = (const float*)d_in[11];
    const float* bn1  = (const float*)d_in[12];
    const float* Wp2  = (const float*)d_in[13];
    const float* bp2  = (const float*)d_in[14];
    const float* Wn2  = (const float*)d_in[15];
    const float* bn2  = (const float*)d_in[16];
    float* out = (float*)d_out;
    (void)in_sizes; (void)n_in; (void)out_size; (void)ws_size;

    char* ws = (char*)d_ws;
    size_t off = 0;
    auto carve = [&](size_t bytes) -> char* {
        char* p = ws + off;
        off = (off + bytes + 255) & ~(size_t)255;
        return p;
    };
    unsigned short* hc   = (unsigned short*)carve((size_t)N_NODES * 224 * 2);
    unsigned short* m_bf = (unsigned short*)carve((size_t)4 * N_NODES * 32 * 2);
    unsigned short* fbf  = (unsigned short*)carve((size_t)N_NODES * FIN * 2);
    unsigned short* Wf   = (unsigned short*)carve((size_t)24 * 7 * 512 * 2);
    int* deg  = (int*)carve((size_t)N_NODES * 4);
    int* rowp = (int*)carve((size_t)(N_NODES + 1) * 4);
    int* pos  = (int*)carve((size_t)N_EDGES * 4);
    int* csr  = (int*)carve((size_t)N_EDGES * 4);
    int* bsum = (int*)carve((size_t)SCAN_B * 4);
    int* boff = (int*)carve((size_t)SCAN_B * 4);
    float* gsum = (float*)carve((size_t)NG * HD * 4);
    int*   gcnt = (int*)carve((size_t)NG * 4);

    // fused prep: fconv + hc-pad + weight repack + deg/gsum zero + gcnt
    prep_k<<<1865, 256, 0, stream>>>(feat, fbf, hc, Wemb, Wp1, Wn1, Wp2, Wn2, Wf,
                                     deg, gsum, gids, gcnt);

    count_k<<<(N_EDGES + 255) / 256, 256, 0, stream>>>(dst, deg, pos);
    scan1_k<<<SCAN_B, 1024, 0, stream>>>(deg, rowp, bsum);
    scan2_k<<<1, 64, 0, stream>>>(bsum, boff, rowp);
    scan3_k<<<SCAN_B, 1024, 0, stream>>>(rowp, boff);
    fill_k<<<(N_EDGES + 255) / 256, 256, 0, stream>>>(src, dst, rowp, pos, csr);

    const int GB = (N_NODES / 16 + 3) / 4;           // 782 blocks x 4 waves
    const int AB = 4 * ((N_NODES + 63) / 64);        // 4 chunks x 782 node-blocks
    unsigned short* Wf_emb = Wf + (size_t)0  * 7 * 512;
    unsigned short* Wf_p1  = Wf + (size_t)2  * 7 * 512;
    unsigned short* Wf_n1  = Wf + (size_t)6  * 7 * 512;
    unsigned short* Wf_p2  = Wf + (size_t)13 * 7 * 512;
    unsigned short* Wf_n2  = Wf + (size_t)17 * 7 * 512;

    // layer 0+1a: embed + pool1 (fused)
    gemm_k<2, 0><<<GB, 256, 0, stream>>>(fbf, FIN, Wf_emb, bemb, Wf_p1, bp1,
                                         hc, m_bf, nullptr, nullptr);
    aggregate_k<<<AB, 256, 0, stream>>>(m_bf, rowp, csr, hc);
    // layer 1b+2a: apply1 + pool2 (fused)
    gemm_k<7, 2><<<GB, 256, 0, stream>>>(hc, 224, Wf_n1, bn1, Wf_p2, bp2,
                                         hc, m_bf, nullptr, nullptr);
    aggregate_k<<<AB, 256, 0, stream>>>(m_bf, rowp, csr, hc);
    // layer 2b: apply2 -> graph sums
    gemm_k<7, 3><<<GB, 256, 0, stream>>>(hc, 224, Wf_n2, bn2, nullptr, nullptr,
                                         hc, nullptr, gids, gsum);

    finalize_k<<<(NG * HD + 255) / 256, 256, 0, stream>>>(gsum, gcnt, out);
}